// Round 6
// baseline (319.487 us; speedup 1.0000x reference)
//
#include <hip/hip_runtime.h>
#include <hip/hip_bf16.h>

#define TSTEPS 60
#define HIDDEN 64

typedef __attribute__((ext_vector_type(8))) short bf16x8;
typedef __attribute__((ext_vector_type(4))) float f32x4;

// Setup-only (loop-invariant) scalar conversion (compiler RNE emulation, cold path).
__device__ __forceinline__ short f2bf(float f) {
    return __builtin_bit_cast(short, __float2bfloat16(f));
}

// Hot-path pack: two f32 -> one u32 of 2 bf16, round-to-nearest (ties away).
// Pure bit ops, no asm (round-5 lesson: v_cvt_pk_bf16_f32 asm gave wrong halves
// -> recurrence exploded to 6.6e36; deterministic across fence configs).
// ~5 VALU for 2 conversions vs ~12 for emulated RNE. Inputs are finite (no NaN).
__device__ __forceinline__ unsigned pack2_bf16(float a, float b) {
    unsigned ua = __builtin_bit_cast(unsigned, a) + 0x8000u;
    unsigned ub = __builtin_bit_cast(unsigned, b) + 0x8000u;
    return (ua >> 16) | (ub & 0xFFFF0000u);
}

// One wave = 16 samples, sequential over TSTEPS.
//   L1: D1 = W1^T(64x4,K-pad32) @ x(4x16)      -> h1 (64x16)
//   L2: D2 = W2^T(64x64)        @ h1(64x16)    -> h2 (64x16)
//   L3: delta = relu(h2) . W3  (VALU dot + shfl_xor reduce over g-groups)
// D-frag: col=lane&15 (sample), row=(lane>>4)*4+reg.  A/B-frags: 8 contig k per lane.
//
// Fences: h1 round-trips through LDS with uint2-typed writes and bf16x8-typed
// reads of the same bytes (TBAA says non-aliasing). The zero-instruction
// compiler fences pin write->read (RAW) and read->next-write (WAR) order.
__global__ __launch_bounds__(256)
void ffn_mfma(const float* __restrict__ feat,
              const float* __restrict__ W1, const float* __restrict__ b1,
              const float* __restrict__ W2, const float* __restrict__ b2,
              const float* __restrict__ W3, const float* __restrict__ b3,
              float* __restrict__ out, int N) {
    __shared__ short h1s[4][1024];  // per-wave 16x64 bf16, XOR-swizzled

    const int lane = threadIdx.x & 63;
    const int wave = threadIdx.x >> 6;
    const int c = lane & 15;     // sample column
    const int g = lane >> 4;     // k/row group
    const int nbase = blockIdx.x * 64 + wave * 16;
    if (nbase >= N) return;

    // ---- loop-invariant weight fragments ----
    // W1^T as A: A[row=c][k=8g+j] = W1[k][m*16+c], zero for k>=4.
    bf16x8 a1[4];
#pragma unroll
    for (int m = 0; m < 4; ++m) {
        bf16x8 v = {0, 0, 0, 0, 0, 0, 0, 0};
        if (g == 0) {
#pragma unroll
            for (int j = 0; j < 4; ++j) v[j] = f2bf(W1[j * 64 + m * 16 + c]);
        }
        a1[m] = v;
    }
    // W2^T as A: A[row=c][k=32q+8g+j] = W2[k][m*16+c].
    bf16x8 a2[4][2];
#pragma unroll
    for (int m = 0; m < 4; ++m)
#pragma unroll
        for (int q = 0; q < 2; ++q) {
            bf16x8 v;
#pragma unroll
            for (int j = 0; j < 8; ++j)
                v[j] = f2bf(W2[(32 * q + 8 * g + j) * 64 + m * 16 + c]);
            a2[m][q] = v;
        }
    // Per-lane bias / W3 fragments in D layout (row = m*16+4g+r).
    f32x4 b1f[4], b2f[4], w3f[4];
#pragma unroll
    for (int m = 0; m < 4; ++m)
#pragma unroll
        for (int r = 0; r < 4; ++r) {
            b1f[m][r] = b1[m * 16 + 4 * g + r];
            b2f[m][r] = b2[m * 16 + 4 * g + r];
            w3f[m][r] = W3[m * 16 + 4 * g + r];
        }
    const float b3v = b3[0];

    // LDS addressing: logical byte (c*128 + hid*2), XOR-swizzled by ((c&7)<<4).
    char* hbase = (char*)&h1s[wave][0];
    const int swz = (c & 7) << 4;
    int woff[4], roff[2];
#pragma unroll
    for (int m = 0; m < 4; ++m) woff[m] = (c * 128 + m * 32 + g * 8) ^ swz;
#pragma unroll
    for (int q = 0; q < 2; ++q) roff[q] = (c * 128 + q * 64 + g * 16) ^ swz;

    const float* fp = feat + (size_t)(nbase + c) * (TSTEPS * 3);
    float* o = out + (size_t)(nbase + c) * TSTEPS;
    float delta = 0.0f;

    auto step = [&](int t) -> float {
        const float f0 = fp[t * 3 + 0];
        const float f1 = fp[t * 3 + 1];
        const float f2 = fp[t * 3 + 2];

        // x-frag (B of L1): rows 0..3 = [f0,f1,f2,delta]; rows>=4 don't care (A is 0).
        uint4 xu;
        xu.x = pack2_bf16(f0, f1);
        xu.y = pack2_bf16(f2, delta);
        xu.z = 0u; xu.w = 0u;
        const bf16x8 xb = __builtin_bit_cast(bf16x8, xu);

        // L1: h1 = relu(W1^T @ x + b1)
        f32x4 h1a[4];
#pragma unroll
        for (int m = 0; m < 4; ++m)
            h1a[m] = __builtin_amdgcn_mfma_f32_16x16x32_bf16(a1[m], xb, b1f[m], 0, 0, 0);

        // relu + pack + LDS write ([c][m*16+4g..+3], 8B each)
#pragma unroll
        for (int m = 0; m < 4; ++m) {
            uint2 u;
            u.x = pack2_bf16(fmaxf(h1a[m][0], 0.f), fmaxf(h1a[m][1], 0.f));
            u.y = pack2_bf16(fmaxf(h1a[m][2], 0.f), fmaxf(h1a[m][3], 0.f));
            *(uint2*)(hbase + woff[m]) = u;
        }
        __asm__ volatile("" ::: "memory");  // RAW fence: reads stay below writes

        // B-frags of L2: lane reads h1[ k=32q+8g..+7 ][c] = 16B contiguous
        const bf16x8 hb0 = *(const bf16x8*)(hbase + roff[0]);
        const bf16x8 hb1 = *(const bf16x8*)(hbase + roff[1]);
        __asm__ volatile("" ::: "memory");  // WAR fence: next step's writes stay below reads

        // L2: h2 = W2^T @ h1 + b2
        f32x4 acc[4];
#pragma unroll
        for (int m = 0; m < 4; ++m) {
            acc[m] = __builtin_amdgcn_mfma_f32_16x16x32_bf16(a2[m][0], hb0, b2f[m], 0, 0, 0);
            acc[m] = __builtin_amdgcn_mfma_f32_16x16x32_bf16(a2[m][1], hb1, acc[m], 0, 0, 0);
        }

        // L3: delta = relu(h2) . W3 + b3  (per-lane partial, reduce over g-groups)
        float p = 0.f;
#pragma unroll
        for (int m = 0; m < 4; ++m)
#pragma unroll
            for (int r = 0; r < 4; ++r)
                p = fmaf(fmaxf(acc[m][r], 0.f), w3f[m][r], p);
        p += __shfl_xor(p, 16, 64);
        p += __shfl_xor(p, 32, 64);
        return p + b3v;
    };

    // t-loop unrolled x4: 4 deltas in named registers -> one float4 store per sample.
    for (int tb = 0; tb < TSTEPS; tb += 4) {
        const float d0 = step(tb + 0); delta = d0;
        const float d1 = step(tb + 1); delta = d1;
        const float d2 = step(tb + 2); delta = d2;
        const float d3 = step(tb + 3); delta = d3;
        if (g == 0) {
            f32x4 v = {d0, d1, d2, d3};
            *(f32x4*)(o + tb) = v;   // (n*60+tb)*4 bytes, 16B-aligned (240 % 16 == 0)
        }
    }
}

extern "C" void kernel_launch(void* const* d_in, const int* in_sizes, int n_in,
                              void* d_out, int out_size, void* d_ws, size_t ws_size,
                              hipStream_t stream) {
    const float* feat = (const float*)d_in[0];
    const float* W1   = (const float*)d_in[1];
    const float* b1   = (const float*)d_in[2];
    const float* W2   = (const float*)d_in[3];
    const float* b2   = (const float*)d_in[4];
    const float* W3   = (const float*)d_in[5];
    const float* b3   = (const float*)d_in[6];
    float* out = (float*)d_out;

    const int N = in_sizes[0] / (TSTEPS * 3);
    const int block = 256;                 // 4 waves x 16 samples = 64 samples/block
    const int grid = (N + 63) / 64;
    ffn_mfma<<<grid, block, 0, stream>>>(feat, W1, b1, W2, b2, W3, b3, out, N);
}